// Round 14
// baseline (64.237 us; speedup 1.0000x reference)
//
#include <hip/hip_runtime.h>

#define JITTER 1e-5f

__device__ __forceinline__ float fast_rcp(float v) {
#if __has_builtin(__builtin_amdgcn_rcpf)
    return __builtin_amdgcn_rcpf(v);
#else
    return 1.0f / v;
#endif
}
// broadcast lane k's value to all 64 lanes via DS pipe (VGPR dest)
__device__ __forceinline__ float bp(float v, int k) {
    return __int_as_float(__builtin_amdgcn_ds_bpermute(k * 4, __float_as_int(v)));
}

// ---------------------------------------------------------------------------
// One kernel, 256 blocks x 512 threads (2 particles/block). r13 structure
// (passed, 27.6us) with the solve upgraded from rank-1 GJ (64 serial steps,
// ~750cyc each: bp->fma dependency pairs leave DS latency exposed) to
// RANK-4 BLOCKED GJ: 16 macro-steps. Per macro-step (pivot base k):
//   P[i][j] = bp(row[k+j], k+i)            (16 independent bpermutes)
//   Pinv    = 4x4 inverse, lane-local via 2x2 Schur complement (~80 VALU)
//   beta_j  = in-block ? Pinv[lane-k][j] : -(rowblk . Pinv)_j ; alpha=0/1
//   row[c]  = alpha*row[c] + sum_j beta_j * bp(row[c], k+j)   (c >= k+4)
//   b       = alpha*b      + sum_j beta_j * bp(b, k+j)
// After 16 macro-steps M -> I exactly: b IS the solution (no final divide).
// Same information flow as r13 (~2300 bpermutes) but 4x shorter serial
// chain and 4-wide independent DS ops per column -> latency amortized.
// Non-pivoted 4x4 inverses are safe: trailing Schur blocks of a PD matrix
// stay PD, diag ~ 1. Epilogue identical to r5/r7/r13 (verified).
// ---------------------------------------------------------------------------
__global__ __launch_bounds__(512) void diag_sgp_fused8(
    const float* __restrict__ x,        // (n,8)
    const float* __restrict__ y,        // (n,32)
    const float* __restrict__ z,        // (n,2048)
    const float* __restrict__ gamma,    // (n,2048)
    const float* __restrict__ inducing, // (64,8)
    const float* __restrict__ Kmat,     // (32,32)
    const float* __restrict__ pvar,
    const float* __restrict__ pls,
    const float* __restrict__ pnoise,
    float* __restrict__ out,            // [m_new (n,2048) | g (n,2048)]
    int n_total)
{
    const int tid = threadIdx.x;
    const int n0  = blockIdx.x * 2;
    const int t8  = tid & 255;           // thread within particle
    const int h   = tid >> 8;            // particle half (0/1)

    // ---- prefetch HBM-heavy operands immediately ----
    const size_t base = (size_t)(n0 + h) * 2048 + t8 * 8;
    const float4 g0 = *reinterpret_cast<const float4*>(gamma + base);
    const float4 g1 = *reinterpret_cast<const float4*>(gamma + base + 4);
    const float4 zv0 = *reinterpret_cast<const float4*>(z + base);
    const float4 zv1 = *reinterpret_cast<const float4*>(z + base + 4);

    __shared__ __align__(16) float Zl[64 * 8];     // inducing, row-major
    __shared__ float Kl[32 * 33];                  // K, pitch 33
    __shared__ float xl[2][8], yl[2][32];
    __shared__ float e_sh[2][64];
    __shared__ __align__(16) float a_sh[2][64];
    __shared__ float t_sh[2][32], rc[2][32], rd[2][32], s1s[2][32], s2s[2][32];
    __shared__ float Bsh[2];

    Zl[tid & 511] = inducing[tid & 511];
    for (int i = tid; i < 1024; i += 512)
        Kl[(i >> 5) * 33 + (i & 31)] = Kmat[i];
    if (tid < 16) xl[tid >> 3][tid & 7]  = x[n0 * 8 + tid];
    if (tid < 64) yl[tid >> 5][tid & 31] = y[n0 * 32 + tid];
    const float var = pvar[0], ls = pls[0], nv = pnoise[0];
    const float sc = 0.5f / (ls * ls);
    __syncthreads();                               // B1

    // ================= wave-0 register GJ solve (row-per-lane) ===========
    if (tid < 64) {
        const int lane = tid;
        float zc[8];
        {
            const float4 za = *reinterpret_cast<const float4*>(inducing + lane * 8);
            const float4 zb = *reinterpret_cast<const float4*>(inducing + lane * 8 + 4);
            zc[0] = za.x; zc[1] = za.y; zc[2] = za.z; zc[3] = za.w;
            zc[4] = zb.x; zc[5] = zb.y; zc[6] = zb.z; zc[7] = zb.w;
        }

        // build rows: row[c] = M[lane][c]; z_c via uniform b128 reads
        float row[64];
#pragma unroll
        for (int c = 0; c < 64; ++c) {
            const float4 r0 = *reinterpret_cast<const float4*>(&Zl[c * 8]);
            const float4 r1 = *reinterpret_cast<const float4*>(&Zl[c * 8 + 4]);
            float sq;
            {
                const float d0 = zc[0] - r0.x; sq  = d0 * d0;
                const float d1 = zc[1] - r0.y; sq = fmaf(d1, d1, sq);
                const float d2 = zc[2] - r0.z; sq = fmaf(d2, d2, sq);
                const float d3 = zc[3] - r0.w; sq = fmaf(d3, d3, sq);
                const float d4 = zc[4] - r1.x; sq = fmaf(d4, d4, sq);
                const float d5 = zc[5] - r1.y; sq = fmaf(d5, d5, sq);
                const float d6 = zc[6] - r1.z; sq = fmaf(d6, d6, sq);
                const float d7 = zc[7] - r1.w; sq = fmaf(d7, d7, sq);
            }
            const float v = __expf(-sq * sc);
            row[c] = (lane == c) ? v + JITTER : v;
        }
        float b0, b1;
        {
            float sq0 = 0.f, sq1 = 0.f;
#pragma unroll
            for (int dd = 0; dd < 8; ++dd) {
                const float d0 = xl[0][dd] - zc[dd]; sq0 = fmaf(d0, d0, sq0);
                const float d1 = xl[1][dd] - zc[dd]; sq1 = fmaf(d1, d1, sq1);
            }
            b0 = __expf(-sq0 * sc);
            b1 = __expf(-sq1 * sc);
        }
        e_sh[0][lane] = b0;
        e_sh[1][lane] = b1;

        // ---- rank-4 blocked GJ elimination ----
#pragma unroll
        for (int m = 0; m < 16; ++m) {
            const int k = m * 4;
            // pivot block P[i][j] = M[k+i][k+j]
            float P[4][4];
#pragma unroll
            for (int i = 0; i < 4; ++i)
#pragma unroll
                for (int j = 0; j < 4; ++j)
                    P[i][j] = bp(row[k + j], k + i);

            // lane-local 4x4 inverse via 2x2 Schur complement
            const float detA = fmaf(P[0][0], P[1][1], -P[0][1] * P[1][0]);
            const float rdA  = fast_rcp(detA);
            const float Ai00 =  P[1][1] * rdA, Ai01 = -P[0][1] * rdA;
            const float Ai10 = -P[1][0] * rdA, Ai11 =  P[0][0] * rdA;
            const float CAi00 = P[2][0] * Ai00 + P[2][1] * Ai10;
            const float CAi01 = P[2][0] * Ai01 + P[2][1] * Ai11;
            const float CAi10 = P[3][0] * Ai00 + P[3][1] * Ai10;
            const float CAi11 = P[3][0] * Ai01 + P[3][1] * Ai11;
            const float AiB00 = Ai00 * P[0][2] + Ai01 * P[1][2];
            const float AiB01 = Ai00 * P[0][3] + Ai01 * P[1][3];
            const float AiB10 = Ai10 * P[0][2] + Ai11 * P[1][2];
            const float AiB11 = Ai10 * P[0][3] + Ai11 * P[1][3];
            const float S00 = P[2][2] - (CAi00 * P[0][2] + CAi01 * P[1][2]);
            const float S01 = P[2][3] - (CAi00 * P[0][3] + CAi01 * P[1][3]);
            const float S10 = P[3][2] - (CAi10 * P[0][2] + CAi11 * P[1][2]);
            const float S11 = P[3][3] - (CAi10 * P[0][3] + CAi11 * P[1][3]);
            const float detS = fmaf(S00, S11, -S01 * S10);
            const float rdS  = fast_rcp(detS);
            const float Si00 =  S11 * rdS, Si01 = -S01 * rdS;
            const float Si10 = -S10 * rdS, Si11 =  S00 * rdS;
            const float SC00 = Si00 * CAi00 + Si01 * CAi10;
            const float SC01 = Si00 * CAi01 + Si01 * CAi11;
            const float SC10 = Si10 * CAi00 + Si11 * CAi10;
            const float SC11 = Si10 * CAi01 + Si11 * CAi11;
            const float AS00 = AiB00 * Si00 + AiB01 * Si10;
            const float AS01 = AiB00 * Si01 + AiB01 * Si11;
            const float AS10 = AiB10 * Si00 + AiB11 * Si10;
            const float AS11 = AiB10 * Si01 + AiB11 * Si11;
            float Pi[4][4];
            Pi[0][0] = Ai00 + (AiB00 * SC00 + AiB01 * SC10);
            Pi[0][1] = Ai01 + (AiB00 * SC01 + AiB01 * SC11);
            Pi[0][2] = -AS00;  Pi[0][3] = -AS01;
            Pi[1][0] = Ai10 + (AiB10 * SC00 + AiB11 * SC10);
            Pi[1][1] = Ai11 + (AiB10 * SC01 + AiB11 * SC11);
            Pi[1][2] = -AS10;  Pi[1][3] = -AS11;
            Pi[2][0] = -SC00;  Pi[2][1] = -SC01;  Pi[2][2] = Si00;  Pi[2][3] = Si01;
            Pi[3][0] = -SC10;  Pi[3][1] = -SC11;  Pi[3][2] = Si10;  Pi[3][3] = Si11;

            // per-lane coefficients: alpha,beta (static reg indices only)
            const bool inblk = (lane >= k) && (lane < k + 4);
            const float alpha = inblk ? 0.f : 1.f;
            float beta[4];
#pragma unroll
            for (int j = 0; j < 4; ++j) {
                const float Fj = -(row[k + 0] * Pi[0][j] + row[k + 1] * Pi[1][j]
                                 + row[k + 2] * Pi[2][j] + row[k + 3] * Pi[3][j]);
                float bj = (lane == k)     ? Pi[0][j]
                         : (lane == k + 1) ? Pi[1][j]
                         : (lane == k + 2) ? Pi[2][j]
                         :                   Pi[3][j];
                beta[j] = inblk ? bj : Fj;
            }

            // RHS update (reads pre-macro values of b)
            {
                const float sb00 = bp(b0, k + 0), sb01 = bp(b0, k + 1);
                const float sb02 = bp(b0, k + 2), sb03 = bp(b0, k + 3);
                const float sb10 = bp(b1, k + 0), sb11 = bp(b1, k + 1);
                const float sb12 = bp(b1, k + 2), sb13 = bp(b1, k + 3);
                float t0 = alpha * b0;
                t0 = fmaf(beta[0], sb00, t0); t0 = fmaf(beta[1], sb01, t0);
                t0 = fmaf(beta[2], sb02, t0); t0 = fmaf(beta[3], sb03, t0);
                float t1 = alpha * b1;
                t1 = fmaf(beta[0], sb10, t1); t1 = fmaf(beta[1], sb11, t1);
                t1 = fmaf(beta[2], sb12, t1); t1 = fmaf(beta[3], sb13, t1);
                b0 = t0; b1 = t1;
            }
            // trailing column updates (cols < k+4 are dead afterwards)
#pragma unroll
            for (int c = k + 4; c < 64; ++c) {
                const float s0 = bp(row[c], k + 0);
                const float s1 = bp(row[c], k + 1);
                const float s2 = bp(row[c], k + 2);
                const float s3 = bp(row[c], k + 3);
                float t = alpha * row[c];
                t = fmaf(beta[0], s0, t);
                t = fmaf(beta[1], s1, t);
                t = fmaf(beta[2], s2, t);
                t = fmaf(beta[3], s3, t);
                row[c] = t;
            }
        }
        a_sh[0][lane] = b0;                        // M -> I, b is the solution
        a_sh[1][lane] = b1;
    }
    __syncthreads();                               // B2

    // ================= verified epilogue, 2 particles =================
    if (t8 < 64) {                                 // waves 0 & 4: B reduce
        float v = e_sh[h][t8] * a_sh[h][t8];
        for (int off = 32; off; off >>= 1) v += __shfl_down(v, off);
        if (t8 == 0) Bsh[h] = var * (1.f - v);
    }

    // t[j] partials via 8-lane shfl tree
    const int jrow = t8 >> 3;
    float ga[8] = {g0.x, g0.y, g0.z, g0.w, g1.x, g1.y, g1.z, g1.w};
    const int ab = (t8 & 7) * 8;
    const float4 a0 = *reinterpret_cast<const float4*>(&a_sh[h][ab]);
    const float4 a1 = *reinterpret_cast<const float4*>(&a_sh[h][ab + 4]);
    const float as[8] = {a0.x, a0.y, a0.z, a0.w, a1.x, a1.y, a1.z, a1.w};

    float pt = 0.f;
#pragma unroll
    for (int e = 0; e < 8; ++e) pt += as[e] * as[e] * ga[e];
    pt += __shfl_xor(pt, 1);
    pt += __shfl_xor(pt, 2);
    pt += __shfl_xor(pt, 4);
    if ((t8 & 7) == 0) t_sh[h][jrow] = pt;
    __syncthreads();                               // B3

    if (t8 < 32) {                                 // c, d per output dim
        float acc = 0.f;
        for (int jj = 0; jj < 32; ++jj) {
            const float kv = Kl[t8 * 33 + jj];
            acc += kv * kv * t_sh[h][jj];
        }
        const float ci = Bsh[h] * Kl[t8 * 34] + nv;
        const float di = acc + ci;
        rc[h][t8] = yl[h][t8] / ci;
        rd[h][t8] = 1.0f / di;
    }
    __syncthreads();                               // B4

    if (t8 < 32) {                                 // s1, s2 per j
        float sa = 0.f, sb = 0.f;
        for (int i = 0; i < 32; ++i) {
            const float kv = Kl[i * 33 + t8];
            sa += kv * rc[h][i];
            sb += kv * kv * rd[h][i];
        }
        s1s[h][t8] = sa;
        s2s[h][t8] = sb;
    }
    __syncthreads();                               // B5

    const float zv[8] = {zv0.x, zv0.y, zv0.z, zv0.w, zv1.x, zv1.y, zv1.z, zv1.w};
    const float s1j = s1s[h][jrow], s2j = s2s[h][jrow];
    float mn[8], gg[8];
#pragma unroll
    for (int e = 0; e < 8; ++e) {
        const float ge = ga[e];
        const float am = as[e];
        const float gm = ge * am;
        const float gv = ge - gm * gm * s2j;
        gg[e] = gv;
        mn[e] = gv * (zv[e] / ge + am * s1j);
    }

    float* o_m = out + base;
    float* o_g = out + (size_t)n_total * 2048 + base;
    *reinterpret_cast<float4*>(o_m)     = make_float4(mn[0], mn[1], mn[2], mn[3]);
    *reinterpret_cast<float4*>(o_m + 4) = make_float4(mn[4], mn[5], mn[6], mn[7]);
    *reinterpret_cast<float4*>(o_g)     = make_float4(gg[0], gg[1], gg[2], gg[3]);
    *reinterpret_cast<float4*>(o_g + 4) = make_float4(gg[4], gg[5], gg[6], gg[7]);
}

extern "C" void kernel_launch(void* const* d_in, const int* in_sizes, int n_in,
                              void* d_out, int out_size, void* d_ws, size_t ws_size,
                              hipStream_t stream)
{
    const float* x        = (const float*)d_in[0];
    const float* y        = (const float*)d_in[1];
    const float* z        = (const float*)d_in[2];
    const float* gamma    = (const float*)d_in[3];
    const float* inducing = (const float*)d_in[4];
    const float* Kmat     = (const float*)d_in[5];
    const float* pvar     = (const float*)d_in[6];
    const float* pls      = (const float*)d_in[7];
    const float* pnoise   = (const float*)d_in[8];
    float* out = (float*)d_out;

    const int n = in_sizes[0] / 8;       // 512
    diag_sgp_fused8<<<dim3(n / 2), dim3(512), 0, stream>>>(
        x, y, z, gamma, inducing, Kmat, pvar, pls, pnoise, out, n);
}

// Round 15
// 42.861 us; speedup vs baseline: 1.4987x; 1.4987x over previous
//
#include <hip/hip_runtime.h>

#define JITTER 1e-5f

__device__ __forceinline__ float fast_rcp(float v) {
#if __has_builtin(__builtin_amdgcn_rcpf)
    return __builtin_amdgcn_rcpf(v);
#else
    return 1.0f / v;
#endif
}
// broadcast lane k's value to all 64 lanes via DS pipe (VGPR dest)
__device__ __forceinline__ float bp(float v, int k) {
    return __int_as_float(__builtin_amdgcn_ds_bpermute(k * 4, __float_as_int(v)));
}

// ---------------------------------------------------------------------------
// One kernel, 512 blocks x 256 threads (ONE particle/block; 2 blocks/CU).
// r14's rank-4 blocked GJ solve -- numerically VERIFIED in r14 (absmax
// 4.9e-4) but spilled there: an 8-wave (512-thread) block caps the compiler
// at 128 VGPRs while the solve needs ~150. A 4-wave block may use up to 512
// VGPRs/wave; at ~160 we keep 2 blocks/CU (512 blocks = 256 CU x 2, exact).
// Single particle also halves RHS bpermutes. Per macro-step (16 total):
//   P = 4x4 pivot block via 16 independent bpermutes
//   Pinv lane-local (2x2 Schur, ~80 VALU, no cross-lane)
//   row[c] = alpha*row[c] + sum_j beta_j * bp(row[c], k+j)   c >= k+4
//   b likewise; after 16 steps M -> I and b IS the solution.
// Epilogue: the r5/r7/r13-verified code, single-particle indexing.
// ---------------------------------------------------------------------------
__global__ __launch_bounds__(256) void diag_sgp_fused9(
    const float* __restrict__ x,        // (n,8)
    const float* __restrict__ y,        // (n,32)
    const float* __restrict__ z,        // (n,2048)
    const float* __restrict__ gamma,    // (n,2048)
    const float* __restrict__ inducing, // (64,8)
    const float* __restrict__ Kmat,     // (32,32)
    const float* __restrict__ pvar,
    const float* __restrict__ pls,
    const float* __restrict__ pnoise,
    float* __restrict__ out,            // [m_new (n,2048) | g (n,2048)]
    int n_total)
{
    const int tid = threadIdx.x;
    const int n   = blockIdx.x;

    // ---- prefetch HBM-heavy operands immediately ----
    const size_t base = (size_t)n * 2048 + tid * 8;
    const float4 g0 = *reinterpret_cast<const float4*>(gamma + base);
    const float4 g1 = *reinterpret_cast<const float4*>(gamma + base + 4);
    const float4 zv0 = *reinterpret_cast<const float4*>(z + base);
    const float4 zv1 = *reinterpret_cast<const float4*>(z + base + 4);

    __shared__ __align__(16) float Zl[64 * 8];     // inducing, row-major
    __shared__ float Kl[32 * 33];                  // K, pitch 33
    __shared__ float xl[8], yl[32];
    __shared__ float e_sh[64];
    __shared__ __align__(16) float a_sh[64];
    __shared__ float t_sh[32], rc[32], rd[32], s1s[32], s2s[32];
    __shared__ float Bsh;

    for (int i = tid; i < 512; i += 256) Zl[i] = inducing[i];
    for (int i = tid; i < 1024; i += 256)
        Kl[(i >> 5) * 33 + (i & 31)] = Kmat[i];
    if (tid < 8)  xl[tid] = x[n * 8 + tid];
    if (tid < 32) yl[tid] = y[n * 32 + tid];
    const float var = pvar[0], ls = pls[0], nv = pnoise[0];
    const float sc = 0.5f / (ls * ls);
    __syncthreads();                               // B1

    // ================= wave-0 register GJ solve (row-per-lane) ===========
    if (tid < 64) {
        const int lane = tid;
        float zc[8];
        {
            const float4 za = *reinterpret_cast<const float4*>(inducing + lane * 8);
            const float4 zb = *reinterpret_cast<const float4*>(inducing + lane * 8 + 4);
            zc[0] = za.x; zc[1] = za.y; zc[2] = za.z; zc[3] = za.w;
            zc[4] = zb.x; zc[5] = zb.y; zc[6] = zb.z; zc[7] = zb.w;
        }

        // build rows: row[c] = M[lane][c]; z_c via uniform b128 reads
        float row[64];
#pragma unroll
        for (int c = 0; c < 64; ++c) {
            const float4 r0 = *reinterpret_cast<const float4*>(&Zl[c * 8]);
            const float4 r1 = *reinterpret_cast<const float4*>(&Zl[c * 8 + 4]);
            float sq;
            {
                const float d0 = zc[0] - r0.x; sq  = d0 * d0;
                const float d1 = zc[1] - r0.y; sq = fmaf(d1, d1, sq);
                const float d2 = zc[2] - r0.z; sq = fmaf(d2, d2, sq);
                const float d3 = zc[3] - r0.w; sq = fmaf(d3, d3, sq);
                const float d4 = zc[4] - r1.x; sq = fmaf(d4, d4, sq);
                const float d5 = zc[5] - r1.y; sq = fmaf(d5, d5, sq);
                const float d6 = zc[6] - r1.z; sq = fmaf(d6, d6, sq);
                const float d7 = zc[7] - r1.w; sq = fmaf(d7, d7, sq);
            }
            const float v = __expf(-sq * sc);
            row[c] = (lane == c) ? v + JITTER : v;
        }
        float b0;
        {
            float sq0 = 0.f;
#pragma unroll
            for (int dd = 0; dd < 8; ++dd) {
                const float d0 = xl[dd] - zc[dd]; sq0 = fmaf(d0, d0, sq0);
            }
            b0 = __expf(-sq0 * sc);
        }
        e_sh[lane] = b0;

        // ---- rank-4 blocked GJ elimination (r14-verified recurrence) ----
#pragma unroll
        for (int m = 0; m < 16; ++m) {
            const int k = m * 4;
            float P[4][4];
#pragma unroll
            for (int i = 0; i < 4; ++i)
#pragma unroll
                for (int j = 0; j < 4; ++j)
                    P[i][j] = bp(row[k + j], k + i);

            // lane-local 4x4 inverse via 2x2 Schur complement
            const float detA = fmaf(P[0][0], P[1][1], -P[0][1] * P[1][0]);
            const float rdA  = fast_rcp(detA);
            const float Ai00 =  P[1][1] * rdA, Ai01 = -P[0][1] * rdA;
            const float Ai10 = -P[1][0] * rdA, Ai11 =  P[0][0] * rdA;
            const float CAi00 = P[2][0] * Ai00 + P[2][1] * Ai10;
            const float CAi01 = P[2][0] * Ai01 + P[2][1] * Ai11;
            const float CAi10 = P[3][0] * Ai00 + P[3][1] * Ai10;
            const float CAi11 = P[3][0] * Ai01 + P[3][1] * Ai11;
            const float AiB00 = Ai00 * P[0][2] + Ai01 * P[1][2];
            const float AiB01 = Ai00 * P[0][3] + Ai01 * P[1][3];
            const float AiB10 = Ai10 * P[0][2] + Ai11 * P[1][2];
            const float AiB11 = Ai10 * P[0][3] + Ai11 * P[1][3];
            const float S00 = P[2][2] - (CAi00 * P[0][2] + CAi01 * P[1][2]);
            const float S01 = P[2][3] - (CAi00 * P[0][3] + CAi01 * P[1][3]);
            const float S10 = P[3][2] - (CAi10 * P[0][2] + CAi11 * P[1][2]);
            const float S11 = P[3][3] - (CAi10 * P[0][3] + CAi11 * P[1][3]);
            const float detS = fmaf(S00, S11, -S01 * S10);
            const float rdS  = fast_rcp(detS);
            const float Si00 =  S11 * rdS, Si01 = -S01 * rdS;
            const float Si10 = -S10 * rdS, Si11 =  S00 * rdS;
            const float SC00 = Si00 * CAi00 + Si01 * CAi10;
            const float SC01 = Si00 * CAi01 + Si01 * CAi11;
            const float SC10 = Si10 * CAi00 + Si11 * CAi10;
            const float SC11 = Si10 * CAi01 + Si11 * CAi11;
            const float AS00 = AiB00 * Si00 + AiB01 * Si10;
            const float AS01 = AiB00 * Si01 + AiB01 * Si11;
            const float AS10 = AiB10 * Si00 + AiB11 * Si10;
            const float AS11 = AiB10 * Si01 + AiB11 * Si11;
            float Pi[4][4];
            Pi[0][0] = Ai00 + (AiB00 * SC00 + AiB01 * SC10);
            Pi[0][1] = Ai01 + (AiB00 * SC01 + AiB01 * SC11);
            Pi[0][2] = -AS00;  Pi[0][3] = -AS01;
            Pi[1][0] = Ai10 + (AiB10 * SC00 + AiB11 * SC10);
            Pi[1][1] = Ai11 + (AiB10 * SC01 + AiB11 * SC11);
            Pi[1][2] = -AS10;  Pi[1][3] = -AS11;
            Pi[2][0] = -SC00;  Pi[2][1] = -SC01;  Pi[2][2] = Si00;  Pi[2][3] = Si01;
            Pi[3][0] = -SC10;  Pi[3][1] = -SC11;  Pi[3][2] = Si10;  Pi[3][3] = Si11;

            const bool inblk = (lane >= k) && (lane < k + 4);
            const float alpha = inblk ? 0.f : 1.f;
            float beta[4];
#pragma unroll
            for (int j = 0; j < 4; ++j) {
                const float Fj = -(row[k + 0] * Pi[0][j] + row[k + 1] * Pi[1][j]
                                 + row[k + 2] * Pi[2][j] + row[k + 3] * Pi[3][j]);
                float bj = (lane == k)     ? Pi[0][j]
                         : (lane == k + 1) ? Pi[1][j]
                         : (lane == k + 2) ? Pi[2][j]
                         :                   Pi[3][j];
                beta[j] = inblk ? bj : Fj;
            }

            // RHS update (pre-macro values)
            {
                const float sb0 = bp(b0, k + 0), sb1 = bp(b0, k + 1);
                const float sb2 = bp(b0, k + 2), sb3 = bp(b0, k + 3);
                float t0 = alpha * b0;
                t0 = fmaf(beta[0], sb0, t0); t0 = fmaf(beta[1], sb1, t0);
                t0 = fmaf(beta[2], sb2, t0); t0 = fmaf(beta[3], sb3, t0);
                b0 = t0;
            }
            // trailing column updates
#pragma unroll
            for (int c = k + 4; c < 64; ++c) {
                const float s0 = bp(row[c], k + 0);
                const float s1 = bp(row[c], k + 1);
                const float s2 = bp(row[c], k + 2);
                const float s3 = bp(row[c], k + 3);
                float t = alpha * row[c];
                t = fmaf(beta[0], s0, t);
                t = fmaf(beta[1], s1, t);
                t = fmaf(beta[2], s2, t);
                t = fmaf(beta[3], s3, t);
                row[c] = t;
            }
        }
        a_sh[lane] = b0;                           // M -> I: b is the solution
    }
    __syncthreads();                               // B2

    // ================= verified epilogue (single particle) ================
    if (tid < 64) {                                // wave 0: B reduce
        float v = e_sh[tid] * a_sh[tid];
        for (int off = 32; off; off >>= 1) v += __shfl_down(v, off);
        if (tid == 0) Bsh = var * (1.f - v);
    }

    // t[j] partials via 8-lane shfl tree
    const int jrow = tid >> 3;
    float ga[8] = {g0.x, g0.y, g0.z, g0.w, g1.x, g1.y, g1.z, g1.w};
    const int ab = (tid & 7) * 8;
    const float4 a0 = *reinterpret_cast<const float4*>(&a_sh[ab]);
    const float4 a1 = *reinterpret_cast<const float4*>(&a_sh[ab + 4]);
    const float as[8] = {a0.x, a0.y, a0.z, a0.w, a1.x, a1.y, a1.z, a1.w};

    float pt = 0.f;
#pragma unroll
    for (int e = 0; e < 8; ++e) pt += as[e] * as[e] * ga[e];
    pt += __shfl_xor(pt, 1);
    pt += __shfl_xor(pt, 2);
    pt += __shfl_xor(pt, 4);
    if ((tid & 7) == 0) t_sh[jrow] = pt;
    __syncthreads();                               // B3

    if (tid < 32) {                                // c, d per output dim
        float acc = 0.f;
        for (int jj = 0; jj < 32; ++jj) {
            const float kv = Kl[tid * 33 + jj];
            acc += kv * kv * t_sh[jj];
        }
        const float ci = Bsh * Kl[tid * 34] + nv;
        const float di = acc + ci;
        rc[tid] = yl[tid] / ci;
        rd[tid] = 1.0f / di;
    }
    __syncthreads();                               // B4

    if (tid < 32) {                                // s1, s2 per j
        float sa = 0.f, sb = 0.f;
        for (int i = 0; i < 32; ++i) {
            const float kv = Kl[i * 33 + tid];
            sa += kv * rc[i];
            sb += kv * kv * rd[i];
        }
        s1s[tid] = sa;
        s2s[tid] = sb;
    }
    __syncthreads();                               // B5

    const float zv[8] = {zv0.x, zv0.y, zv0.z, zv0.w, zv1.x, zv1.y, zv1.z, zv1.w};
    const float s1j = s1s[jrow], s2j = s2s[jrow];
    float mn[8], gg[8];
#pragma unroll
    for (int e = 0; e < 8; ++e) {
        const float ge = ga[e];
        const float am = as[e];
        const float gm = ge * am;
        const float gv = ge - gm * gm * s2j;
        gg[e] = gv;
        mn[e] = gv * (zv[e] / ge + am * s1j);
    }

    float* o_m = out + base;
    float* o_g = out + (size_t)n_total * 2048 + base;
    *reinterpret_cast<float4*>(o_m)     = make_float4(mn[0], mn[1], mn[2], mn[3]);
    *reinterpret_cast<float4*>(o_m + 4) = make_float4(mn[4], mn[5], mn[6], mn[7]);
    *reinterpret_cast<float4*>(o_g)     = make_float4(gg[0], gg[1], gg[2], gg[3]);
    *reinterpret_cast<float4*>(o_g + 4) = make_float4(gg[4], gg[5], gg[6], gg[7]);
}

extern "C" void kernel_launch(void* const* d_in, const int* in_sizes, int n_in,
                              void* d_out, int out_size, void* d_ws, size_t ws_size,
                              hipStream_t stream)
{
    const float* x        = (const float*)d_in[0];
    const float* y        = (const float*)d_in[1];
    const float* z        = (const float*)d_in[2];
    const float* gamma    = (const float*)d_in[3];
    const float* inducing = (const float*)d_in[4];
    const float* Kmat     = (const float*)d_in[5];
    const float* pvar     = (const float*)d_in[6];
    const float* pls      = (const float*)d_in[7];
    const float* pnoise   = (const float*)d_in[8];
    float* out = (float*)d_out;

    const int n = in_sizes[0] / 8;       // 512
    diag_sgp_fused9<<<dim3(n), dim3(256), 0, stream>>>(
        x, y, z, gamma, inducing, Kmat, pvar, pls, pnoise, out, n);
}